// Round 6
// baseline (191.861 us; speedup 1.0000x reference)
//
#include <hip/hip_runtime.h>

#define DIM 128
#define NGRAPH 256

// partition geometry
#define CHUNK 512            // nodes per coarse bucket
#define CHB 9                // log2(CHUNK)
#define MAXNB 256            // max coarse buckets -> supports N <= 131072
#define EPB 4096             // edges per partition block
#define EPT (EPB / 256)      // edges per thread in k_part
#define FCAP 14336           // max edges per bucket staged in LDS

typedef __attribute__((ext_vector_type(8))) short short8;
typedef __attribute__((ext_vector_type(4))) float f32x4;

// ===========================================================================
// f32 -> bf16 (RNE) pack helpers
// ===========================================================================
__device__ inline unsigned int bpack2(float lo, float hi) {
  unsigned int ul = __float_as_uint(lo);
  unsigned int uh = __float_as_uint(hi);
  ul = (ul + 0x7fffu + ((ul >> 16) & 1u)) >> 16;
  uh = (uh + 0x7fffu + ((uh >> 16) & 1u)) & 0xffff0000u;
  return ul | uh;
}

// ===========================================================================
// Fused prep: H f32 -> two bf16 half-row arrays (dims 0-63 / 64-127), plus
// the coarse-bucket histogram for blocks < NBLK (both memory-bound streams).
// ===========================================================================
__global__ __launch_bounds__(256) void k_prep(const float4* __restrict__ H4,
    uint2* __restrict__ Hb0, uint2* __restrict__ Hb1, int n4,
    const int* __restrict__ dst, unsigned short* __restrict__ bh, int E,
    int NBLK) {
  __shared__ unsigned int hist[MAXNB];
  int blk = blockIdx.x, t = threadIdx.x;
  int i = blk * 256 + t;
  if (i < n4) {
    float4 a = H4[i];
    uint2 r;
    r.x = bpack2(a.x, a.y);
    r.y = bpack2(a.z, a.w);
    int node = i >> 5, c4 = i & 31;
    uint2* dest = (c4 < 16) ? Hb0 : Hb1;
    dest[(size_t)node * 16 + (c4 & 15)] = r;
  }
  if (blk < NBLK) {
    hist[t] = 0;
    __syncthreads();
    int base = blk * EPB;
#pragma unroll
    for (int k = 0; k < EPT; ++k) {
      int e = base + k * 256 + t;
      if (e < E) atomicAdd(&hist[((unsigned)dst[e]) >> CHB], 1);
    }
    __syncthreads();
    bh[(size_t)blk * MAXNB + t] = (unsigned short)hist[t];
  }
}

// standalone histogram (csr path without bf16 workspace)
__global__ __launch_bounds__(256) void k_bhist(const int* __restrict__ dst,
    unsigned short* __restrict__ bh, int E) {
  __shared__ unsigned int hist[MAXNB];
  int blk = blockIdx.x, t = threadIdx.x;
  hist[t] = 0;
  __syncthreads();
  int base = blk * EPB;
#pragma unroll
  for (int i = 0; i < EPT; ++i) {
    int e = base + i * 256 + t;
    if (e < E) atomicAdd(&hist[((unsigned)dst[e]) >> CHB], 1);
  }
  __syncthreads();
  bh[(size_t)blk * MAXNB + t] = (unsigned short)hist[t];
}

// ===========================================================================
// Pass S1: per-bucket exclusive scan over blocks (in place) + totals
// ===========================================================================
__global__ __launch_bounds__(256) void k_bscan(unsigned short* __restrict__ bh,
    unsigned int* __restrict__ btot, int NBLK) {
  __shared__ unsigned int tmp[256];
  int b = blockIdx.x, t = threadIdx.x;
  int i0 = 2 * t, i1 = 2 * t + 1;
  unsigned int a0 = (i0 < NBLK) ? bh[(size_t)i0 * MAXNB + b] : 0u;
  unsigned int a1 = (i1 < NBLK) ? bh[(size_t)i1 * MAXNB + b] : 0u;
  unsigned int ps = a0 + a1;
  tmp[t] = ps;
  __syncthreads();
  for (int off = 1; off < 256; off <<= 1) {
    unsigned int x = (t >= off) ? tmp[t - off] : 0u;
    __syncthreads();
    tmp[t] += x;
    __syncthreads();
  }
  unsigned int ex = tmp[t] - ps;
  if (i0 < NBLK) bh[(size_t)i0 * MAXNB + b] = (unsigned short)ex;
  if (i1 < NBLK) bh[(size_t)i1 * MAXNB + b] = (unsigned short)(ex + a0);
  if (t == 255) btot[b] = tmp[255];
}

// ===========================================================================
// Pass S2: exclusive scan of bucket totals -> bucket bases; offs[N]=E
// ===========================================================================
__global__ __launch_bounds__(256) void k_bscan2(const unsigned int* __restrict__ btot,
    unsigned int* __restrict__ bbase, int* __restrict__ offs, int N, int E) {
  __shared__ unsigned int s[256];
  int t = threadIdx.x;
  unsigned int v = btot[t];
  s[t] = v;
  __syncthreads();
  for (int off = 1; off < 256; off <<= 1) {
    unsigned int x = (t >= off) ? s[t - off] : 0u;
    __syncthreads();
    s[t] += x;
    __syncthreads();
  }
  bbase[t] = s[t] - v;
  if (t == 255) { bbase[256] = s[255]; offs[N] = E; }
}

// ===========================================================================
// Pass B: LDS multisplit into coarse buckets (no global atomics)
// ===========================================================================
__global__ __launch_bounds__(256) void k_part(const int* __restrict__ src,
    const int* __restrict__ dst, const unsigned short* __restrict__ bh,
    const unsigned int* __restrict__ bbase, unsigned int* __restrict__ pack, int E) {
  __shared__ unsigned int hist[MAXNB];
  __shared__ unsigned int sc[MAXNB];
  __shared__ unsigned int gbase[MAXNB];
  __shared__ unsigned int lpack[EPB];
  __shared__ unsigned short lbkt[EPB];
  __shared__ unsigned int totS;
  int blk = blockIdx.x, t = threadIdx.x;
  hist[t] = 0;
  __syncthreads();

  int base = blk * EPB;
  unsigned int pk[EPT];
  int bk[EPT];
  unsigned int rk[EPT];
#pragma unroll
  for (int i = 0; i < EPT; ++i) {
    int e = base + i * 256 + t;
    if (e < E) {
      unsigned int s = (unsigned)src[e], d = (unsigned)dst[e];
      pk[i] = (s << CHB) | (d & (CHUNK - 1));
      int b = (int)(d >> CHB);
      bk[i] = b;
      rk[i] = atomicAdd(&hist[b], 1u);
    } else {
      bk[i] = -1;
    }
  }
  __syncthreads();

  unsigned int c = hist[t];
  sc[t] = c;
  __syncthreads();
  for (int off = 1; off < 256; off <<= 1) {
    unsigned int x = (t >= off) ? sc[t - off] : 0u;
    __syncthreads();
    sc[t] += x;
    __syncthreads();
  }
  if (t == 255) totS = sc[255];
  hist[t] = sc[t] - c;
  gbase[t] = bbase[t] + (unsigned int)bh[(size_t)blk * MAXNB + t];
  __syncthreads();

#pragma unroll
  for (int i = 0; i < EPT; ++i) {
    if (bk[i] >= 0) {
      unsigned int slot = hist[bk[i]] + rk[i];
      lpack[slot] = pk[i];
      lbkt[slot] = (unsigned short)bk[i];
    }
  }
  __syncthreads();

  unsigned int tot = totS;
  for (unsigned int s = t; s < tot; s += 256) {
    int b = lbkt[s];
    unsigned int local = s - hist[b];
    pack[gbase[b] + local] = lpack[s];
  }
}

// ===========================================================================
// Pass C: fine CSR within each bucket
// ===========================================================================
__global__ __launch_bounds__(256) void k_fine(unsigned int* __restrict__ pack,
    const unsigned int* __restrict__ bbase, int* __restrict__ offs, int N) {
  __shared__ unsigned int lp[FCAP];
  __shared__ unsigned int cnt[CHUNK];
  __shared__ unsigned int cur[CHUNK];
  __shared__ unsigned int tmp[256];
  int b = blockIdx.x, t = threadIdx.x;
  unsigned int lo = bbase[b], hi = bbase[b + 1];
  int n = (int)(hi - lo);
  if (n > FCAP) n = FCAP;
  cnt[2 * t] = 0; cnt[2 * t + 1] = 0;
  __syncthreads();
  for (int i = t; i < n; i += 256) {
    unsigned int p = pack[lo + i];
    lp[i] = p;
    atomicAdd(&cnt[p & (CHUNK - 1)], 1u);
  }
  __syncthreads();
  unsigned int c0 = cnt[2 * t], c1 = cnt[2 * t + 1];
  unsigned int ps = c0 + c1;
  tmp[t] = ps;
  __syncthreads();
  for (int off = 1; off < 256; off <<= 1) {
    unsigned int x = (t >= off) ? tmp[t - off] : 0u;
    __syncthreads();
    tmp[t] += x;
    __syncthreads();
  }
  unsigned int ex = tmp[t] - ps;
  cur[2 * t] = ex;
  cur[2 * t + 1] = ex + c0;
  __syncthreads();
  int nb0 = b * CHUNK;
#pragma unroll
  for (int j = t; j < CHUNK; j += 256) {
    int node = nb0 + j;
    if (node < N) offs[node] = (int)(lo + cur[j]);
  }
  __syncthreads();
  for (int i = t; i < n; i += 256) {
    unsigned int p = lp[i];
    unsigned int r = atomicAdd(&cur[p & (CHUNK - 1)], 1u);
    pack[lo + r] = p;
  }
}

// ===========================================================================
// Gather pass over one 64-dim half: wave = node; 4 groups of 16 lanes
// (uint2 = 4 bf16/lane = 128B half-row); 4 edges in flight, 4-deep unroll.
// Working set per pass = 12.8MB -> better per-XCD L2 hit rate.
// ===========================================================================
__device__ inline void bacc(uint2 v, float4& a) {
  a.x += __uint_as_float(v.x << 16);
  a.y += __uint_as_float(v.x & 0xffff0000u);
  a.z += __uint_as_float(v.y << 16);
  a.w += __uint_as_float(v.y & 0xffff0000u);
}

__global__ __launch_bounds__(256) void k_gather2(const float* __restrict__ H,
    const uint2* __restrict__ Hbp, const int* __restrict__ offs,
    const unsigned int* __restrict__ pack, float* __restrict__ out,
    int n, int half) {
  int gid = blockIdx.x * 256 + threadIdx.x;
  int node = gid >> 6;
  if (node >= n) return;
  int lane = threadIdx.x & 63;
  int grp = lane >> 4, q = lane & 15;
  float4 A = {0,0,0,0}, B = {0,0,0,0}, C = {0,0,0,0}, D = {0,0,0,0};
  int beg = offs[node], end = offs[node + 1];
  int j = beg + grp;
  for (; j + 12 < end; j += 16) {
    uint2 v0 = Hbp[(size_t)(pack[j + 0] >> CHB) * 16 + q];
    uint2 v1 = Hbp[(size_t)(pack[j + 4] >> CHB) * 16 + q];
    uint2 v2 = Hbp[(size_t)(pack[j + 8] >> CHB) * 16 + q];
    uint2 v3 = Hbp[(size_t)(pack[j + 12] >> CHB) * 16 + q];
    bacc(v0, A); bacc(v1, B); bacc(v2, C); bacc(v3, D);
  }
  for (; j < end; j += 4) bacc(Hbp[(size_t)(pack[j] >> CHB) * 16 + q], A);
  A.x += B.x + (C.x + D.x);
  A.y += B.y + (C.y + D.y);
  A.z += B.z + (C.z + D.z);
  A.w += B.w + (C.w + D.w);
  A.x += __shfl_xor(A.x, 16);
  A.y += __shfl_xor(A.y, 16);
  A.z += __shfl_xor(A.z, 16);
  A.w += __shfl_xor(A.w, 16);
  A.x += __shfl_xor(A.x, 32);
  A.y += __shfl_xor(A.y, 32);
  A.z += __shfl_xor(A.z, 32);
  A.w += __shfl_xor(A.w, 32);
  if (grp == 0) {
    float4 b4 = ((const float4*)H)[(size_t)node * 32 + half * 16 + q];
    float4 r;
    r.x = b4.x + A.x; r.y = b4.y + A.y; r.z = b4.z + A.z; r.w = b4.w + A.w;
    ((float4*)out)[(size_t)node * 32 + half * 16 + q] = r;
  }
}

// f32 gather fallback (if ws can't hold Hb halves)
__global__ __launch_bounds__(256) void k_gather(const float* __restrict__ H,
    const int* __restrict__ offs, const unsigned int* __restrict__ pack,
    float* __restrict__ out, int n) {
  int gid = blockIdx.x * 256 + threadIdx.x;
  int node = gid >> 6;
  if (node >= n) return;
  int lane = threadIdx.x & 63;
  const float2* H2 = (const float2*)H;
  float2 base = H2[(size_t)node * 64 + lane];
  float2 s0 = {0.f, 0.f}, s1 = {0.f, 0.f}, s2 = {0.f, 0.f}, s3 = {0.f, 0.f};
  int beg = offs[node], end = offs[node + 1];
  int j = beg;
  for (; j + 4 <= end; j += 4) {
    int n0 = (int)(pack[j + 0] >> CHB);
    int n1 = (int)(pack[j + 1] >> CHB);
    int n2 = (int)(pack[j + 2] >> CHB);
    int n3 = (int)(pack[j + 3] >> CHB);
    float2 v0 = H2[(size_t)n0 * 64 + lane];
    float2 v1 = H2[(size_t)n1 * 64 + lane];
    float2 v2 = H2[(size_t)n2 * 64 + lane];
    float2 v3 = H2[(size_t)n3 * 64 + lane];
    s0.x += v0.x; s0.y += v0.y;
    s1.x += v1.x; s1.y += v1.y;
    s2.x += v2.x; s2.y += v2.y;
    s3.x += v3.x; s3.y += v3.y;
  }
  for (; j < end; ++j) {
    float2 v = H2[(size_t)(pack[j] >> CHB) * 64 + lane];
    s0.x += v.x; s0.y += v.y;
  }
  float2 r;
  r.x = base.x + ((s0.x + s1.x) + (s2.x + s3.x));
  r.y = base.y + ((s0.y + s1.y) + (s2.y + s3.y));
  ((float2*)out)[(size_t)node * 64 + lane] = r;
}

// ===========================================================================
// Atomic fallback path
// ===========================================================================
__global__ __launch_bounds__(256) void k_init(const float4* __restrict__ s,
                                              float4* __restrict__ d, int n4) {
  int i = blockIdx.x * 256 + threadIdx.x;
  if (i < n4) d[i] = s[i];
}

__global__ __launch_bounds__(256) void k_scatter(const float* __restrict__ H,
    const int* __restrict__ src, const int* __restrict__ dst,
    float* __restrict__ out, int nE) {
  long long idx = (long long)blockIdx.x * 256 + threadIdx.x;
  int e = (int)(idx >> 5);
  if (e >= nE) return;
  int q = (int)(idx & 31);
  int s = src[e];
  int t = dst[e];
  const float4 h = *(const float4*)(H + (size_t)s * DIM + q * 4);
  float* o = out + (size_t)t * DIM + q * 4;
  unsafeAtomicAdd(o + 0, h.x);
  unsafeAtomicAdd(o + 1, h.y);
  unsafeAtomicAdd(o + 2, h.z);
  unsafeAtomicAdd(o + 3, h.w);
}

// ===========================================================================
// per-graph mean: grid = graph * 4 dim-chunks; float4 loads; LDS tree reduce
// ===========================================================================
__global__ __launch_bounds__(256) void k_vmean4(const float* __restrict__ x,
    const int* __restrict__ batch, float* __restrict__ vmean, int n) {
  int g = blockIdx.x >> 2, c = blockIdx.x & 3;
  int lo = 0, hi = n;
  while (lo < hi) { int m = (lo + hi) >> 1; if (batch[m] < g) lo = m + 1; else hi = m; }
  int start = lo;
  hi = n;
  while (lo < hi) { int m = (lo + hi) >> 1; if (batch[m] < g + 1) lo = m + 1; else hi = m; }
  int end = lo;

  int t = threadIdx.x, rg = t >> 3, s = t & 7;
  int d4 = c * 8 + s;
  const float4* x4 = (const float4*)x;
  float4 acc = {0,0,0,0};
  for (int r = start + rg; r < end; r += 32) {
    float4 v = x4[(size_t)r * 32 + d4];
    acc.x += v.x; acc.y += v.y; acc.z += v.z; acc.w += v.w;
  }
  __shared__ float4 sd[256];
  sd[t] = acc;
  __syncthreads();
  for (int off = 16; off >= 1; off >>= 1) {
    if (rg < off) {
      float4 o = sd[t + off * 8];
      acc.x += o.x; acc.y += o.y; acc.z += o.z; acc.w += o.w;
      sd[t] = acc;
    }
    __syncthreads();
  }
  if (rg == 0) {
    float cnt = fmaxf((float)(end - start), 1.0f);
    float4 r;
    r.x = acc.x / cnt; r.y = acc.y / cnt; r.z = acc.z / cnt; r.w = acc.w / cnt;
    ((float4*)vmean)[g * 32 + d4] = r;
  }
}

// ===========================================================================
// W prep: W[k][c] f32 -> Wt bf16 [col][k], 16B chunks, XOR-swizzled
// ===========================================================================
__global__ __launch_bounds__(256) void k_wprep(const float* __restrict__ W,
                                               uint4* __restrict__ wt) {
  int gid = blockIdx.x * 256 + threadIdx.x;  // 0..2047
  int col = gid >> 4, chunk = gid & 15;
  float f[8];
#pragma unroll
  for (int j = 0; j < 8; ++j) f[j] = W[(chunk * 8 + j) * DIM + col];
  uint4 u;
  u.x = bpack2(f[0], f[1]);
  u.y = bpack2(f[2], f[3]);
  u.z = bpack2(f[4], f[5]);
  u.w = bpack2(f[6], f[7]);
  wt[col * 16 + (chunk ^ (col & 7))] = u;
}

// ===========================================================================
// MFMA GEMM: out = relu((out1 + vmean[batch]) @ W), in place on d_out.
// ===========================================================================
__global__ __launch_bounds__(256) void k_mfma(float* __restrict__ io,
    const int* __restrict__ batch, const float* __restrict__ vmean,
    const uint4* __restrict__ wt, int n) {
  __shared__ uint4 WtL[2048];
  int tid = threadIdx.x;
#pragma unroll
  for (int j = 0; j < 8; ++j) WtL[tid + 256 * j] = wt[tid + 256 * j];
  __syncthreads();

  int wid = tid >> 6;
  int lane = tid & 63;
  int q = lane & 15, hi = lane >> 4;
  int row0 = blockIdx.x * 128 + wid * 32;

  f32x4 acc[2][8];
#pragma unroll
  for (int m = 0; m < 2; ++m)
#pragma unroll
    for (int nn = 0; nn < 8; ++nn) acc[m][nn] = (f32x4){0.f, 0.f, 0.f, 0.f};

  bool okm[2];
  const float4* xrow[2];
  const float4* vrow[2];
#pragma unroll
  for (int m = 0; m < 2; ++m) {
    int row = row0 + m * 16 + q;
    bool ok = row < n;
    okm[m] = ok;
    int g = ok ? batch[row] : 0;
    xrow[m] = (const float4*)io + (size_t)row * 32;
    vrow[m] = (const float4*)vmean + (size_t)g * 32;
  }

  for (int kk = 0; kk < 4; ++kk) {
    short8 Bf[8];
#pragma unroll
    for (int nn = 0; nn < 8; ++nn) {
      int colrow = nn * 16 + q;
      int idx = colrow * 16 + ((kk * 4 + hi) ^ (colrow & 7));
      Bf[nn] = *(short8*)&WtL[idx];
    }
    short8 Af[2];
#pragma unroll
    for (int m = 0; m < 2; ++m) {
      float4 x0 = {0,0,0,0}, x1 = {0,0,0,0};
      if (okm[m]) {
        int c = kk * 8 + hi * 2;
        float4 a0 = xrow[m][c], a1 = xrow[m][c + 1];
        float4 v0 = vrow[m][c], v1 = vrow[m][c + 1];
        x0.x = a0.x + v0.x; x0.y = a0.y + v0.y; x0.z = a0.z + v0.z; x0.w = a0.w + v0.w;
        x1.x = a1.x + v1.x; x1.y = a1.y + v1.y; x1.z = a1.z + v1.z; x1.w = a1.w + v1.w;
      }
      uint4 u;
      u.x = bpack2(x0.x, x0.y);
      u.y = bpack2(x0.z, x0.w);
      u.z = bpack2(x1.x, x1.y);
      u.w = bpack2(x1.z, x1.w);
      Af[m] = *(short8*)&u;
    }
#pragma unroll
    for (int nn = 0; nn < 8; ++nn) {
      acc[0][nn] = __builtin_amdgcn_mfma_f32_16x16x32_bf16(Af[0], Bf[nn], acc[0][nn], 0, 0, 0);
      acc[1][nn] = __builtin_amdgcn_mfma_f32_16x16x32_bf16(Af[1], Bf[nn], acc[1][nn], 0, 0, 0);
    }
  }

#pragma unroll
  for (int m = 0; m < 2; ++m) {
    int grow0 = row0 + m * 16 + hi * 4;
#pragma unroll
    for (int nn = 0; nn < 8; ++nn) {
      int gcol = nn * 16 + q;
      f32x4 c = acc[m][nn];
#pragma unroll
      for (int r = 0; r < 4; ++r) {
        int grow = grow0 + r;
        if (grow < n) io[(size_t)grow * DIM + gcol] = fmaxf(c[r], 0.f);
      }
    }
  }
}

// ===========================================================================
// f32 vector GEMM fallback (only if ws can't hold wt)
// ===========================================================================
#define TRR 64
__global__ __launch_bounds__(256) void k_gemm(float* __restrict__ io,
    const int* __restrict__ batch, const float* __restrict__ vmean,
    const float* __restrict__ W, int n) {
  __shared__ float xs[TRR][DIM + 1];
  __shared__ float Wl[DIM][64];
  int tid = threadIdx.x;
  int row0 = blockIdx.x * TRR;

  for (int i = tid; i < TRR * 32; i += 256) {
    int r = i >> 5, c4 = i & 31;
    int row = row0 + r;
    float4 a;
    if (row < n) {
      int g = batch[row];
      float4 xv = *((const float4*)(io + (size_t)row * DIM) + c4);
      float4 vv = *((const float4*)(vmean + (size_t)g * DIM) + c4);
      a.x = xv.x + vv.x; a.y = xv.y + vv.y; a.z = xv.z + vv.z; a.w = xv.w + vv.w;
    } else {
      a.x = a.y = a.z = a.w = 0.f;
    }
    xs[r][c4 * 4 + 0] = a.x;
    xs[r][c4 * 4 + 1] = a.y;
    xs[r][c4 * 4 + 2] = a.z;
    xs[r][c4 * 4 + 3] = a.w;
  }

  int cg = tid & 15;
  int rg = tid >> 4;
  float acc[4][4];

  for (int jh = 0; jh < 2; ++jh) {
    __syncthreads();
    for (int i = tid; i < DIM * 16; i += 256) {
      int k = i >> 4, c4 = i & 15;
      *(float4*)&Wl[k][c4 * 4] =
          *(const float4*)(W + (size_t)k * DIM + jh * 64 + c4 * 4);
    }
    __syncthreads();

#pragma unroll
    for (int a = 0; a < 4; ++a)
#pragma unroll
      for (int b = 0; b < 4; ++b) acc[a][b] = 0.f;

    for (int k = 0; k < DIM; ++k) {
      float4 wv = *(const float4*)&Wl[k][cg * 4];
#pragma unroll
      for (int a = 0; a < 4; ++a) {
        float xv = xs[rg * 4 + a][k];
        acc[a][0] += xv * wv.x;
        acc[a][1] += xv * wv.y;
        acc[a][2] += xv * wv.z;
        acc[a][3] += xv * wv.w;
      }
    }

#pragma unroll
    for (int a = 0; a < 4; ++a) {
      int row = row0 + rg * 4 + a;
      if (row < n) {
        float4 o;
        o.x = fmaxf(acc[a][0], 0.f);
        o.y = fmaxf(acc[a][1], 0.f);
        o.z = fmaxf(acc[a][2], 0.f);
        o.w = fmaxf(acc[a][3], 0.f);
        *(float4*)(io + (size_t)row * DIM + jh * 64 + cg * 4) = o;
      }
    }
  }
}

// ===========================================================================
extern "C" void kernel_launch(void* const* d_in, const int* in_sizes, int n_in,
                              void* d_out, int out_size, void* d_ws, size_t ws_size,
                              hipStream_t stream) {
  const float* H     = (const float*)d_in[0];
  const int*   ei    = (const int*)d_in[1];
  const int*   batch = (const int*)d_in[2];
  const float* W     = (const float*)d_in[3];
  float* out = (float*)d_out;

  int N = in_sizes[0] / DIM;
  int E = in_sizes[1] / 2;
  const int* src = ei;
  const int* dst = ei + E;

  int NB   = (N + CHUNK - 1) >> CHB;
  int NBLK = (E + EPB - 1) / EPB;

  size_t o = 0;
  auto carve = [&](size_t bytes) -> void* {
    void* p = (char*)d_ws + o;
    o = (o + bytes + 255) & ~(size_t)255;
    return p;
  };
  unsigned int*   pack  = (unsigned int*)carve((size_t)E * 4);
  int*            offs  = (int*)carve(((size_t)N + 1) * 4);
  unsigned short* bh    = (unsigned short*)carve((size_t)NBLK * MAXNB * 2);
  unsigned int*   btot  = (unsigned int*)carve(MAXNB * 4);
  unsigned int*   bbase = (unsigned int*)carve((MAXNB + 1) * 4);
  size_t o_csr = o;
  uint2*          Hb0   = (uint2*)carve((size_t)N * DIM);       // dims 0-63 bf16
  uint2*          Hb1   = (uint2*)carve((size_t)N * DIM);       // dims 64-127
  size_t o_bf = o;
  uint4*          wt    = (uint4*)carve((size_t)DIM * DIM * 2);
  size_t o_wt = o;
  float* vmean = (float*)bh;  // overlays bh (dead after k_part)

  bool csr_ok = (o_csr <= ws_size) && (NB >= 1) && (NB <= MAXNB) &&
                (NBLK <= 512) && ((size_t)NBLK * MAXNB * 2 >= (size_t)NGRAPH * DIM * 4) &&
                (E / NB <= 8192);
  bool bf_ok = csr_ok && (o_bf <= ws_size);
  bool wt_ok = bf_ok && (o_wt <= ws_size) && (DIM == 128);

  if (csr_ok) {
    if (bf_ok) {
      int n4 = N * DIM / 4;
      int gprep = (n4 + 255) / 256;
      if (gprep < NBLK) gprep = NBLK;
      k_prep<<<gprep, 256, 0, stream>>>((const float4*)H, Hb0, Hb1, n4, dst, bh, E, NBLK);
    } else {
      k_bhist<<<NBLK, 256, 0, stream>>>(dst, bh, E);
    }
    k_bscan<<<MAXNB, 256, 0, stream>>>(bh, btot, NBLK);
    k_bscan2<<<1, 256, 0, stream>>>(btot, bbase, offs, N, E);
    k_part<<<NBLK, 256, 0, stream>>>(src, dst, bh, bbase, pack, E);
    k_fine<<<NB, 256, 0, stream>>>(pack, bbase, offs, N);
    long long gthreads = (long long)N * 64;
    int gblocks = (int)((gthreads + 255) / 256);
    if (bf_ok) {
      k_gather2<<<gblocks, 256, 0, stream>>>(H, Hb0, offs, pack, out, N, 0);
      k_gather2<<<gblocks, 256, 0, stream>>>(H, Hb1, offs, pack, out, N, 1);
    } else {
      k_gather<<<gblocks, 256, 0, stream>>>(H, offs, pack, out, N);
    }
  } else {
    vmean = (float*)d_ws;
    int n4 = N * DIM / 4;
    k_init<<<(n4 + 255) / 256, 256, 0, stream>>>((const float4*)H, (float4*)out, n4);
    long long sthreads = (long long)E * 32;
    k_scatter<<<(int)((sthreads + 255) / 256), 256, 0, stream>>>(H, src, dst, out, E);
  }

  k_vmean4<<<NGRAPH * 4, 256, 0, stream>>>(out, batch, vmean, N);

  if (wt_ok) {
    k_wprep<<<8, 256, 0, stream>>>(W, wt);
    k_mfma<<<(N + 127) / 128, 256, 0, stream>>>(out, batch, vmean, wt, N);
  } else {
    k_gemm<<<(N + TRR - 1) / TRR, 256, 0, stream>>>(out, batch, vmean, W, N);
  }
}

// Round 7
// 159.126 us; speedup vs baseline: 1.2057x; 1.2057x over previous
//
#include <hip/hip_runtime.h>

#define DIM 128
#define NGRAPH 256

// partition geometry
#define CHUNK 512            // nodes per coarse bucket
#define CHB 9                // log2(CHUNK)
#define MAXNB 256            // max coarse buckets -> supports N <= 131072
#define EPB 4096             // edges per partition block
#define EPT (EPB / 256)      // edges per thread in k_part
#define FCAP 14336           // max edges per bucket staged in LDS

typedef __attribute__((ext_vector_type(8))) short short8;
typedef __attribute__((ext_vector_type(4))) float f32x4;

// ===========================================================================
// f32 <-> bf16 helpers
// ===========================================================================
__device__ inline unsigned int bpack2(float lo, float hi) {
  unsigned int ul = __float_as_uint(lo);
  unsigned int uh = __float_as_uint(hi);
  ul = (ul + 0x7fffu + ((ul >> 16) & 1u)) >> 16;
  uh = (uh + 0x7fffu + ((uh >> 16) & 1u)) & 0xffff0000u;
  return ul | uh;
}

__device__ inline float4 bunpack4(uint2 v) {
  float4 r;
  r.x = __uint_as_float(v.x << 16);
  r.y = __uint_as_float(v.x & 0xffff0000u);
  r.z = __uint_as_float(v.y << 16);
  r.w = __uint_as_float(v.y & 0xffff0000u);
  return r;
}

// ===========================================================================
// Fused prep: H f32 -> Hb bf16 (single array), + coarse histogram
// ===========================================================================
__global__ __launch_bounds__(256) void k_prep(const float4* __restrict__ H4,
    uint2* __restrict__ Hb, int n4,
    const int* __restrict__ dst, unsigned short* __restrict__ bh, int E,
    int NBLK) {
  __shared__ unsigned int hist[MAXNB];
  int blk = blockIdx.x, t = threadIdx.x;
  int i = blk * 256 + t;
  if (i < n4) {
    float4 a = H4[i];
    uint2 r;
    r.x = bpack2(a.x, a.y);
    r.y = bpack2(a.z, a.w);
    Hb[i] = r;
  }
  if (blk < NBLK) {
    hist[t] = 0;
    __syncthreads();
    int base = blk * EPB;
#pragma unroll
    for (int k = 0; k < EPT; ++k) {
      int e = base + k * 256 + t;
      if (e < E) atomicAdd(&hist[((unsigned)dst[e]) >> CHB], 1);
    }
    __syncthreads();
    bh[(size_t)blk * MAXNB + t] = (unsigned short)hist[t];
  }
}

// standalone histogram (csr path without bf16 workspace)
__global__ __launch_bounds__(256) void k_bhist(const int* __restrict__ dst,
    unsigned short* __restrict__ bh, int E) {
  __shared__ unsigned int hist[MAXNB];
  int blk = blockIdx.x, t = threadIdx.x;
  hist[t] = 0;
  __syncthreads();
  int base = blk * EPB;
#pragma unroll
  for (int i = 0; i < EPT; ++i) {
    int e = base + i * 256 + t;
    if (e < E) atomicAdd(&hist[((unsigned)dst[e]) >> CHB], 1);
  }
  __syncthreads();
  bh[(size_t)blk * MAXNB + t] = (unsigned short)hist[t];
}

// ===========================================================================
// Pass S1: per-bucket exclusive scan over blocks (in place) + totals
// ===========================================================================
__global__ __launch_bounds__(256) void k_bscan(unsigned short* __restrict__ bh,
    unsigned int* __restrict__ btot, int NBLK) {
  __shared__ unsigned int tmp[256];
  int b = blockIdx.x, t = threadIdx.x;
  int i0 = 2 * t, i1 = 2 * t + 1;
  unsigned int a0 = (i0 < NBLK) ? bh[(size_t)i0 * MAXNB + b] : 0u;
  unsigned int a1 = (i1 < NBLK) ? bh[(size_t)i1 * MAXNB + b] : 0u;
  unsigned int ps = a0 + a1;
  tmp[t] = ps;
  __syncthreads();
  for (int off = 1; off < 256; off <<= 1) {
    unsigned int x = (t >= off) ? tmp[t - off] : 0u;
    __syncthreads();
    tmp[t] += x;
    __syncthreads();
  }
  unsigned int ex = tmp[t] - ps;
  if (i0 < NBLK) bh[(size_t)i0 * MAXNB + b] = (unsigned short)ex;
  if (i1 < NBLK) bh[(size_t)i1 * MAXNB + b] = (unsigned short)(ex + a0);
  if (t == 255) btot[b] = tmp[255];
}

// ===========================================================================
// Pass S2: exclusive scan of bucket totals -> bucket bases; offs[N]=E
// ===========================================================================
__global__ __launch_bounds__(256) void k_bscan2(const unsigned int* __restrict__ btot,
    unsigned int* __restrict__ bbase, int* __restrict__ offs, int N, int E) {
  __shared__ unsigned int s[256];
  int t = threadIdx.x;
  unsigned int v = btot[t];
  s[t] = v;
  __syncthreads();
  for (int off = 1; off < 256; off <<= 1) {
    unsigned int x = (t >= off) ? s[t - off] : 0u;
    __syncthreads();
    s[t] += x;
    __syncthreads();
  }
  bbase[t] = s[t] - v;
  if (t == 255) { bbase[256] = s[255]; offs[N] = E; }
}

// ===========================================================================
// Pass B: LDS multisplit into coarse buckets (no global atomics)
// ===========================================================================
__global__ __launch_bounds__(256) void k_part(const int* __restrict__ src,
    const int* __restrict__ dst, const unsigned short* __restrict__ bh,
    const unsigned int* __restrict__ bbase, unsigned int* __restrict__ pack, int E) {
  __shared__ unsigned int hist[MAXNB];
  __shared__ unsigned int sc[MAXNB];
  __shared__ unsigned int gbase[MAXNB];
  __shared__ unsigned int lpack[EPB];
  __shared__ unsigned short lbkt[EPB];
  __shared__ unsigned int totS;
  int blk = blockIdx.x, t = threadIdx.x;
  hist[t] = 0;
  __syncthreads();

  int base = blk * EPB;
  unsigned int pk[EPT];
  int bk[EPT];
  unsigned int rk[EPT];
#pragma unroll
  for (int i = 0; i < EPT; ++i) {
    int e = base + i * 256 + t;
    if (e < E) {
      unsigned int s = (unsigned)src[e], d = (unsigned)dst[e];
      pk[i] = (s << CHB) | (d & (CHUNK - 1));
      int b = (int)(d >> CHB);
      bk[i] = b;
      rk[i] = atomicAdd(&hist[b], 1u);
    } else {
      bk[i] = -1;
    }
  }
  __syncthreads();

  unsigned int c = hist[t];
  sc[t] = c;
  __syncthreads();
  for (int off = 1; off < 256; off <<= 1) {
    unsigned int x = (t >= off) ? sc[t - off] : 0u;
    __syncthreads();
    sc[t] += x;
    __syncthreads();
  }
  if (t == 255) totS = sc[255];
  hist[t] = sc[t] - c;
  gbase[t] = bbase[t] + (unsigned int)bh[(size_t)blk * MAXNB + t];
  __syncthreads();

#pragma unroll
  for (int i = 0; i < EPT; ++i) {
    if (bk[i] >= 0) {
      unsigned int slot = hist[bk[i]] + rk[i];
      lpack[slot] = pk[i];
      lbkt[slot] = (unsigned short)bk[i];
    }
  }
  __syncthreads();

  unsigned int tot = totS;
  for (unsigned int s = t; s < tot; s += 256) {
    int b = lbkt[s];
    unsigned int local = s - hist[b];
    pack[gbase[b] + local] = lpack[s];
  }
}

// ===========================================================================
// Pass C: fine CSR within each bucket
// ===========================================================================
__global__ __launch_bounds__(256) void k_fine(unsigned int* __restrict__ pack,
    const unsigned int* __restrict__ bbase, int* __restrict__ offs, int N) {
  __shared__ unsigned int lp[FCAP];
  __shared__ unsigned int cnt[CHUNK];
  __shared__ unsigned int cur[CHUNK];
  __shared__ unsigned int tmp[256];
  int b = blockIdx.x, t = threadIdx.x;
  unsigned int lo = bbase[b], hi = bbase[b + 1];
  int n = (int)(hi - lo);
  if (n > FCAP) n = FCAP;
  cnt[2 * t] = 0; cnt[2 * t + 1] = 0;
  __syncthreads();
  for (int i = t; i < n; i += 256) {
    unsigned int p = pack[lo + i];
    lp[i] = p;
    atomicAdd(&cnt[p & (CHUNK - 1)], 1u);
  }
  __syncthreads();
  unsigned int c0 = cnt[2 * t], c1 = cnt[2 * t + 1];
  unsigned int ps = c0 + c1;
  tmp[t] = ps;
  __syncthreads();
  for (int off = 1; off < 256; off <<= 1) {
    unsigned int x = (t >= off) ? tmp[t - off] : 0u;
    __syncthreads();
    tmp[t] += x;
    __syncthreads();
  }
  unsigned int ex = tmp[t] - ps;
  cur[2 * t] = ex;
  cur[2 * t + 1] = ex + c0;
  __syncthreads();
  int nb0 = b * CHUNK;
#pragma unroll
  for (int j = t; j < CHUNK; j += 256) {
    int node = nb0 + j;
    if (node < N) offs[node] = (int)(lo + cur[j]);
  }
  __syncthreads();
  for (int i = t; i < n; i += 256) {
    unsigned int p = lp[i];
    unsigned int r = atomicAdd(&cur[p & (CHUNK - 1)], 1u);
    pack[lo + r] = p;
  }
}

// ===========================================================================
// Gather (bf16 in / bf16 out): wave = node; 32 lanes x uint2 cover the 256B
// row; the two half-waves process even/odd edges; writes Hx = bf16(out1).
// ===========================================================================
__device__ inline void bacc(uint2 v, float4& a) {
  a.x += __uint_as_float(v.x << 16);
  a.y += __uint_as_float(v.x & 0xffff0000u);
  a.z += __uint_as_float(v.y << 16);
  a.w += __uint_as_float(v.y & 0xffff0000u);
}

__global__ __launch_bounds__(256) void k_gatherbx(const uint2* __restrict__ Hb,
    const int* __restrict__ offs, const unsigned int* __restrict__ pack,
    uint2* __restrict__ Hx, int n) {
  int gid = blockIdx.x * 256 + threadIdx.x;
  int node = gid >> 6;
  if (node >= n) return;
  int lane = threadIdx.x & 63;
  int half = lane >> 5, q = lane & 31;
  float4 A = {0,0,0,0}, B = {0,0,0,0}, C = {0,0,0,0}, D = {0,0,0,0};
  int beg = offs[node], end = offs[node + 1];
  int j = beg + half;
  for (; j + 6 < end; j += 8) {
    uint2 v0 = Hb[(size_t)(pack[j + 0] >> CHB) * 32 + q];
    uint2 v1 = Hb[(size_t)(pack[j + 2] >> CHB) * 32 + q];
    uint2 v2 = Hb[(size_t)(pack[j + 4] >> CHB) * 32 + q];
    uint2 v3 = Hb[(size_t)(pack[j + 6] >> CHB) * 32 + q];
    bacc(v0, A); bacc(v1, B); bacc(v2, C); bacc(v3, D);
  }
  for (; j < end; j += 2) bacc(Hb[(size_t)(pack[j] >> CHB) * 32 + q], A);
  A.x += B.x + (C.x + D.x);
  A.y += B.y + (C.y + D.y);
  A.z += B.z + (C.z + D.z);
  A.w += B.w + (C.w + D.w);
  A.x += __shfl_xor(A.x, 32);
  A.y += __shfl_xor(A.y, 32);
  A.z += __shfl_xor(A.z, 32);
  A.w += __shfl_xor(A.w, 32);
  if (half == 0) {
    float4 b4 = bunpack4(Hb[(size_t)node * 32 + q]);
    uint2 o;
    o.x = bpack2(b4.x + A.x, b4.y + A.y);
    o.y = bpack2(b4.z + A.z, b4.w + A.w);
    Hx[(size_t)node * 32 + q] = o;
  }
}

// f32-out variant (R5 path, used when Hx doesn't fit in ws)
__global__ __launch_bounds__(256) void k_gatherb(const float* __restrict__ H,
    const uint2* __restrict__ Hb, const int* __restrict__ offs,
    const unsigned int* __restrict__ pack, float* __restrict__ out, int n) {
  int gid = blockIdx.x * 256 + threadIdx.x;
  int node = gid >> 6;
  if (node >= n) return;
  int lane = threadIdx.x & 63;
  int half = lane >> 5, q = lane & 31;
  float4 A = {0,0,0,0}, B = {0,0,0,0}, C = {0,0,0,0}, D = {0,0,0,0};
  int beg = offs[node], end = offs[node + 1];
  int j = beg + half;
  for (; j + 6 < end; j += 8) {
    uint2 v0 = Hb[(size_t)(pack[j + 0] >> CHB) * 32 + q];
    uint2 v1 = Hb[(size_t)(pack[j + 2] >> CHB) * 32 + q];
    uint2 v2 = Hb[(size_t)(pack[j + 4] >> CHB) * 32 + q];
    uint2 v3 = Hb[(size_t)(pack[j + 6] >> CHB) * 32 + q];
    bacc(v0, A); bacc(v1, B); bacc(v2, C); bacc(v3, D);
  }
  for (; j < end; j += 2) bacc(Hb[(size_t)(pack[j] >> CHB) * 32 + q], A);
  A.x += B.x + (C.x + D.x);
  A.y += B.y + (C.y + D.y);
  A.z += B.z + (C.z + D.z);
  A.w += B.w + (C.w + D.w);
  A.x += __shfl_xor(A.x, 32);
  A.y += __shfl_xor(A.y, 32);
  A.z += __shfl_xor(A.z, 32);
  A.w += __shfl_xor(A.w, 32);
  if (half == 0) {
    float4 b4 = ((const float4*)H)[(size_t)node * 32 + q];
    float4 r;
    r.x = b4.x + A.x; r.y = b4.y + A.y; r.z = b4.z + A.z; r.w = b4.w + A.w;
    ((float4*)out)[(size_t)node * 32 + q] = r;
  }
}

// f32 gather fallback (no bf16 ws at all)
__global__ __launch_bounds__(256) void k_gather(const float* __restrict__ H,
    const int* __restrict__ offs, const unsigned int* __restrict__ pack,
    float* __restrict__ out, int n) {
  int gid = blockIdx.x * 256 + threadIdx.x;
  int node = gid >> 6;
  if (node >= n) return;
  int lane = threadIdx.x & 63;
  const float2* H2 = (const float2*)H;
  float2 base = H2[(size_t)node * 64 + lane];
  float2 s0 = {0.f, 0.f}, s1 = {0.f, 0.f};
  int beg = offs[node], end = offs[node + 1];
  int j = beg;
  for (; j + 2 <= end; j += 2) {
    float2 v0 = H2[(size_t)(pack[j + 0] >> CHB) * 64 + lane];
    float2 v1 = H2[(size_t)(pack[j + 1] >> CHB) * 64 + lane];
    s0.x += v0.x; s0.y += v0.y;
    s1.x += v1.x; s1.y += v1.y;
  }
  for (; j < end; ++j) {
    float2 v = H2[(size_t)(pack[j] >> CHB) * 64 + lane];
    s0.x += v.x; s0.y += v.y;
  }
  float2 r;
  r.x = base.x + s0.x + s1.x;
  r.y = base.y + s0.y + s1.y;
  ((float2*)out)[(size_t)node * 64 + lane] = r;
}

// ===========================================================================
// Atomic fallback path
// ===========================================================================
__global__ __launch_bounds__(256) void k_init(const float4* __restrict__ s,
                                              float4* __restrict__ d, int n4) {
  int i = blockIdx.x * 256 + threadIdx.x;
  if (i < n4) d[i] = s[i];
}

__global__ __launch_bounds__(256) void k_scatter(const float* __restrict__ H,
    const int* __restrict__ src, const int* __restrict__ dst,
    float* __restrict__ out, int nE) {
  long long idx = (long long)blockIdx.x * 256 + threadIdx.x;
  int e = (int)(idx >> 5);
  if (e >= nE) return;
  int q = (int)(idx & 31);
  int s = src[e];
  int t = dst[e];
  const float4 h = *(const float4*)(H + (size_t)s * DIM + q * 4);
  float* o = out + (size_t)t * DIM + q * 4;
  unsafeAtomicAdd(o + 0, h.x);
  unsafeAtomicAdd(o + 1, h.y);
  unsafeAtomicAdd(o + 2, h.z);
  unsafeAtomicAdd(o + 3, h.w);
}

// ===========================================================================
// per-graph mean from bf16 Hx: grid = graph * 4 dim-chunks
// ===========================================================================
__global__ __launch_bounds__(256) void k_vmean4x(const uint2* __restrict__ hx,
    const int* __restrict__ batch, float* __restrict__ vmean, int n) {
  int g = blockIdx.x >> 2, c = blockIdx.x & 3;
  int lo = 0, hi = n;
  while (lo < hi) { int m = (lo + hi) >> 1; if (batch[m] < g) lo = m + 1; else hi = m; }
  int start = lo;
  hi = n;
  while (lo < hi) { int m = (lo + hi) >> 1; if (batch[m] < g + 1) lo = m + 1; else hi = m; }
  int end = lo;

  int t = threadIdx.x, rg = t >> 3, s = t & 7;
  int d4 = c * 8 + s;
  float4 acc = {0,0,0,0};
  for (int r = start + rg; r < end; r += 32) {
    float4 v = bunpack4(hx[(size_t)r * 32 + d4]);
    acc.x += v.x; acc.y += v.y; acc.z += v.z; acc.w += v.w;
  }
  __shared__ float4 sd[256];
  sd[t] = acc;
  __syncthreads();
  for (int off = 16; off >= 1; off >>= 1) {
    if (rg < off) {
      float4 o = sd[t + off * 8];
      acc.x += o.x; acc.y += o.y; acc.z += o.z; acc.w += o.w;
      sd[t] = acc;
    }
    __syncthreads();
  }
  if (rg == 0) {
    float cnt = fmaxf((float)(end - start), 1.0f);
    float4 r;
    r.x = acc.x / cnt; r.y = acc.y / cnt; r.z = acc.z / cnt; r.w = acc.w / cnt;
    ((float4*)vmean)[g * 32 + d4] = r;
  }
}

// f32 variant (fallback paths)
__global__ __launch_bounds__(256) void k_vmean4(const float* __restrict__ x,
    const int* __restrict__ batch, float* __restrict__ vmean, int n) {
  int g = blockIdx.x >> 2, c = blockIdx.x & 3;
  int lo = 0, hi = n;
  while (lo < hi) { int m = (lo + hi) >> 1; if (batch[m] < g) lo = m + 1; else hi = m; }
  int start = lo;
  hi = n;
  while (lo < hi) { int m = (lo + hi) >> 1; if (batch[m] < g + 1) lo = m + 1; else hi = m; }
  int end = lo;

  int t = threadIdx.x, rg = t >> 3, s = t & 7;
  int d4 = c * 8 + s;
  const float4* x4 = (const float4*)x;
  float4 acc = {0,0,0,0};
  for (int r = start + rg; r < end; r += 32) {
    float4 v = x4[(size_t)r * 32 + d4];
    acc.x += v.x; acc.y += v.y; acc.z += v.z; acc.w += v.w;
  }
  __shared__ float4 sd[256];
  sd[t] = acc;
  __syncthreads();
  for (int off = 16; off >= 1; off >>= 1) {
    if (rg < off) {
      float4 o = sd[t + off * 8];
      acc.x += o.x; acc.y += o.y; acc.z += o.z; acc.w += o.w;
      sd[t] = acc;
    }
    __syncthreads();
  }
  if (rg == 0) {
    float cnt = fmaxf((float)(end - start), 1.0f);
    float4 r;
    r.x = acc.x / cnt; r.y = acc.y / cnt; r.z = acc.z / cnt; r.w = acc.w / cnt;
    ((float4*)vmean)[g * 32 + d4] = r;
  }
}

// ===========================================================================
// W prep: W[k][c] f32 -> Wt bf16 [col][k], 16B chunks, XOR-swizzled
// ===========================================================================
__global__ __launch_bounds__(256) void k_wprep(const float* __restrict__ W,
                                               uint4* __restrict__ wt) {
  int gid = blockIdx.x * 256 + threadIdx.x;  // 0..2047
  int col = gid >> 4, chunk = gid & 15;
  float f[8];
#pragma unroll
  for (int j = 0; j < 8; ++j) f[j] = W[(chunk * 8 + j) * DIM + col];
  uint4 u;
  u.x = bpack2(f[0], f[1]);
  u.y = bpack2(f[2], f[3]);
  u.z = bpack2(f[4], f[5]);
  u.w = bpack2(f[6], f[7]);
  wt[col * 16 + (chunk ^ (col & 7))] = u;
}

// ===========================================================================
// MFMA GEMM from bf16 Hx: out = relu((Hx + vmean[batch]) @ W) -> d_out f32.
// A-frag = one uint4 of Hx (8 bf16 = one K-slice), unpack, +vmean, repack.
// ===========================================================================
__global__ __launch_bounds__(256) void k_mfmax(const uint4* __restrict__ Hx,
    float* __restrict__ io, const int* __restrict__ batch,
    const float* __restrict__ vmean, const uint4* __restrict__ wt, int n) {
  __shared__ uint4 WtL[2048];
  int tid = threadIdx.x;
#pragma unroll
  for (int j = 0; j < 8; ++j) WtL[tid + 256 * j] = wt[tid + 256 * j];
  __syncthreads();

  int wid = tid >> 6;
  int lane = tid & 63;
  int q = lane & 15, hi = lane >> 4;
  int row0 = blockIdx.x * 128 + wid * 32;

  f32x4 acc[2][8];
#pragma unroll
  for (int m = 0; m < 2; ++m)
#pragma unroll
    for (int nn = 0; nn < 8; ++nn) acc[m][nn] = (f32x4){0.f, 0.f, 0.f, 0.f};

  bool okm[2];
  const uint4* xrow[2];
  const float4* vrow[2];
#pragma unroll
  for (int m = 0; m < 2; ++m) {
    int row = row0 + m * 16 + q;
    bool ok = row < n;
    okm[m] = ok;
    int g = ok ? batch[row] : 0;
    xrow[m] = Hx + (size_t)row * 16;
    vrow[m] = (const float4*)vmean + (size_t)g * 32;
  }

  for (int kk = 0; kk < 4; ++kk) {
    short8 Bf[8];
#pragma unroll
    for (int nn = 0; nn < 8; ++nn) {
      int colrow = nn * 16 + q;
      int idx = colrow * 16 + ((kk * 4 + hi) ^ (colrow & 7));
      Bf[nn] = *(short8*)&WtL[idx];
    }
    short8 Af[2];
#pragma unroll
    for (int m = 0; m < 2; ++m) {
      uint4 u = {0, 0, 0, 0};
      if (okm[m]) {
        uint4 xv = xrow[m][kk * 4 + hi];
        float4 x0 = bunpack4(*(uint2*)&xv.x);
        float4 x1 = bunpack4(*(uint2*)&xv.z);
        int c = kk * 8 + hi * 2;
        float4 v0 = vrow[m][c], v1 = vrow[m][c + 1];
        u.x = bpack2(x0.x + v0.x, x0.y + v0.y);
        u.y = bpack2(x0.z + v0.z, x0.w + v0.w);
        u.z = bpack2(x1.x + v1.x, x1.y + v1.y);
        u.w = bpack2(x1.z + v1.z, x1.w + v1.w);
      }
      Af[m] = *(short8*)&u;
    }
#pragma unroll
    for (int nn = 0; nn < 8; ++nn) {
      acc[0][nn] = __builtin_amdgcn_mfma_f32_16x16x32_bf16(Af[0], Bf[nn], acc[0][nn], 0, 0, 0);
      acc[1][nn] = __builtin_amdgcn_mfma_f32_16x16x32_bf16(Af[1], Bf[nn], acc[1][nn], 0, 0, 0);
    }
  }

#pragma unroll
  for (int m = 0; m < 2; ++m) {
    int grow0 = row0 + m * 16 + hi * 4;
#pragma unroll
    for (int nn = 0; nn < 8; ++nn) {
      int gcol = nn * 16 + q;
      f32x4 c = acc[m][nn];
#pragma unroll
      for (int r = 0; r < 4; ++r) {
        int grow = grow0 + r;
        if (grow < n) io[(size_t)grow * DIM + gcol] = fmaxf(c[r], 0.f);
      }
    }
  }
}

// f32-input variant (R5 path: X = d_out in place)
__global__ __launch_bounds__(256) void k_mfma(float* __restrict__ io,
    const int* __restrict__ batch, const float* __restrict__ vmean,
    const uint4* __restrict__ wt, int n) {
  __shared__ uint4 WtL[2048];
  int tid = threadIdx.x;
#pragma unroll
  for (int j = 0; j < 8; ++j) WtL[tid + 256 * j] = wt[tid + 256 * j];
  __syncthreads();

  int wid = tid >> 6;
  int lane = tid & 63;
  int q = lane & 15, hi = lane >> 4;
  int row0 = blockIdx.x * 128 + wid * 32;

  f32x4 acc[2][8];
#pragma unroll
  for (int m = 0; m < 2; ++m)
#pragma unroll
    for (int nn = 0; nn < 8; ++nn) acc[m][nn] = (f32x4){0.f, 0.f, 0.f, 0.f};

  bool okm[2];
  const float4* xrow[2];
  const float4* vrow[2];
#pragma unroll
  for (int m = 0; m < 2; ++m) {
    int row = row0 + m * 16 + q;
    bool ok = row < n;
    okm[m] = ok;
    int g = ok ? batch[row] : 0;
    xrow[m] = (const float4*)io + (size_t)row * 32;
    vrow[m] = (const float4*)vmean + (size_t)g * 32;
  }

  for (int kk = 0; kk < 4; ++kk) {
    short8 Bf[8];
#pragma unroll
    for (int nn = 0; nn < 8; ++nn) {
      int colrow = nn * 16 + q;
      int idx = colrow * 16 + ((kk * 4 + hi) ^ (colrow & 7));
      Bf[nn] = *(short8*)&WtL[idx];
    }
    short8 Af[2];
#pragma unroll
    for (int m = 0; m < 2; ++m) {
      float4 x0 = {0,0,0,0}, x1 = {0,0,0,0};
      if (okm[m]) {
        int c = kk * 8 + hi * 2;
        float4 a0 = xrow[m][c], a1 = xrow[m][c + 1];
        float4 v0 = vrow[m][c], v1 = vrow[m][c + 1];
        x0.x = a0.x + v0.x; x0.y = a0.y + v0.y; x0.z = a0.z + v0.z; x0.w = a0.w + v0.w;
        x1.x = a1.x + v1.x; x1.y = a1.y + v1.y; x1.z = a1.z + v1.z; x1.w = a1.w + v1.w;
      }
      uint4 u;
      u.x = bpack2(x0.x, x0.y);
      u.y = bpack2(x0.z, x0.w);
      u.z = bpack2(x1.x, x1.y);
      u.w = bpack2(x1.z, x1.w);
      Af[m] = *(short8*)&u;
    }
#pragma unroll
    for (int nn = 0; nn < 8; ++nn) {
      acc[0][nn] = __builtin_amdgcn_mfma_f32_16x16x32_bf16(Af[0], Bf[nn], acc[0][nn], 0, 0, 0);
      acc[1][nn] = __builtin_amdgcn_mfma_f32_16x16x32_bf16(Af[1], Bf[nn], acc[1][nn], 0, 0, 0);
    }
  }

#pragma unroll
  for (int m = 0; m < 2; ++m) {
    int grow0 = row0 + m * 16 + hi * 4;
#pragma unroll
    for (int nn = 0; nn < 8; ++nn) {
      int gcol = nn * 16 + q;
      f32x4 c = acc[m][nn];
#pragma unroll
      for (int r = 0; r < 4; ++r) {
        int grow = grow0 + r;
        if (grow < n) io[(size_t)grow * DIM + gcol] = fmaxf(c[r], 0.f);
      }
    }
  }
}

// ===========================================================================
// f32 vector GEMM fallback (only if ws can't hold wt)
// ===========================================================================
#define TRR 64
__global__ __launch_bounds__(256) void k_gemm(float* __restrict__ io,
    const int* __restrict__ batch, const float* __restrict__ vmean,
    const float* __restrict__ W, int n) {
  __shared__ float xs[TRR][DIM + 1];
  __shared__ float Wl[DIM][64];
  int tid = threadIdx.x;
  int row0 = blockIdx.x * TRR;

  for (int i = tid; i < TRR * 32; i += 256) {
    int r = i >> 5, c4 = i & 31;
    int row = row0 + r;
    float4 a;
    if (row < n) {
      int g = batch[row];
      float4 xv = *((const float4*)(io + (size_t)row * DIM) + c4);
      float4 vv = *((const float4*)(vmean + (size_t)g * DIM) + c4);
      a.x = xv.x + vv.x; a.y = xv.y + vv.y; a.z = xv.z + vv.z; a.w = xv.w + vv.w;
    } else {
      a.x = a.y = a.z = a.w = 0.f;
    }
    xs[r][c4 * 4 + 0] = a.x;
    xs[r][c4 * 4 + 1] = a.y;
    xs[r][c4 * 4 + 2] = a.z;
    xs[r][c4 * 4 + 3] = a.w;
  }

  int cg = tid & 15;
  int rg = tid >> 4;
  float acc[4][4];

  for (int jh = 0; jh < 2; ++jh) {
    __syncthreads();
    for (int i = tid; i < DIM * 16; i += 256) {
      int k = i >> 4, c4 = i & 15;
      *(float4*)&Wl[k][c4 * 4] =
          *(const float4*)(W + (size_t)k * DIM + jh * 64 + c4 * 4);
    }
    __syncthreads();

#pragma unroll
    for (int a = 0; a < 4; ++a)
#pragma unroll
      for (int b = 0; b < 4; ++b) acc[a][b] = 0.f;

    for (int k = 0; k < DIM; ++k) {
      float4 wv = *(const float4*)&Wl[k][cg * 4];
#pragma unroll
      for (int a = 0; a < 4; ++a) {
        float xv = xs[rg * 4 + a][k];
        acc[a][0] += xv * wv.x;
        acc[a][1] += xv * wv.y;
        acc[a][2] += xv * wv.z;
        acc[a][3] += xv * wv.w;
      }
    }

#pragma unroll
    for (int a = 0; a < 4; ++a) {
      int row = row0 + rg * 4 + a;
      if (row < n) {
        float4 o;
        o.x = fmaxf(acc[a][0], 0.f);
        o.y = fmaxf(acc[a][1], 0.f);
        o.z = fmaxf(acc[a][2], 0.f);
        o.w = fmaxf(acc[a][3], 0.f);
        *(float4*)(io + (size_t)row * DIM + jh * 64 + cg * 4) = o;
      }
    }
  }
}

// ===========================================================================
extern "C" void kernel_launch(void* const* d_in, const int* in_sizes, int n_in,
                              void* d_out, int out_size, void* d_ws, size_t ws_size,
                              hipStream_t stream) {
  const float* H     = (const float*)d_in[0];
  const int*   ei    = (const int*)d_in[1];
  const int*   batch = (const int*)d_in[2];
  const float* W     = (const float*)d_in[3];
  float* out = (float*)d_out;

  int N = in_sizes[0] / DIM;
  int E = in_sizes[1] / 2;
  const int* src = ei;
  const int* dst = ei + E;

  int NB   = (N + CHUNK - 1) >> CHB;
  int NBLK = (E + EPB - 1) / EPB;

  size_t o = 0;
  auto carve = [&](size_t bytes) -> void* {
    void* p = (char*)d_ws + o;
    o = (o + bytes + 255) & ~(size_t)255;
    return p;
  };
  unsigned int*   pack  = (unsigned int*)carve((size_t)E * 4);
  int*            offs  = (int*)carve(((size_t)N + 1) * 4);
  unsigned short* bh    = (unsigned short*)carve((size_t)NBLK * MAXNB * 2);
  unsigned int*   btot  = (unsigned int*)carve(MAXNB * 4);
  unsigned int*   bbase = (unsigned int*)carve((MAXNB + 1) * 4);
  size_t o_csr = o;
  uint2*          Hb    = (uint2*)carve((size_t)N * DIM * 2);   // bf16 H
  size_t o_bf = o;
  uint4*          wt    = (uint4*)carve((size_t)DIM * DIM * 2);
  size_t o_wt = o;
  uint2*          Hx    = (uint2*)carve((size_t)N * DIM * 2);   // bf16 out1
  size_t o_hx = o;
  float* vmean = (float*)bh;  // overlays bh (dead after k_part)

  bool csr_ok = (o_csr <= ws_size) && (NB >= 1) && (NB <= MAXNB) &&
                (NBLK <= 512) && ((size_t)NBLK * MAXNB * 2 >= (size_t)NGRAPH * DIM * 4) &&
                (E / NB <= 8192);
  bool bf_ok = csr_ok && (o_bf <= ws_size);
  bool wt_ok = bf_ok && (o_wt <= ws_size) && (DIM == 128);
  bool hx_ok = wt_ok && (o_hx <= ws_size);

  if (csr_ok) {
    if (bf_ok) {
      int n4 = N * DIM / 4;
      int gprep = (n4 + 255) / 256;
      if (gprep < NBLK) gprep = NBLK;
      k_prep<<<gprep, 256, 0, stream>>>((const float4*)H, Hb, n4, dst, bh, E, NBLK);
    } else {
      k_bhist<<<NBLK, 256, 0, stream>>>(dst, bh, E);
    }
    k_bscan<<<MAXNB, 256, 0, stream>>>(bh, btot, NBLK);
    k_bscan2<<<1, 256, 0, stream>>>(btot, bbase, offs, N, E);
    k_part<<<NBLK, 256, 0, stream>>>(src, dst, bh, bbase, pack, E);
    k_fine<<<NB, 256, 0, stream>>>(pack, bbase, offs, N);
    long long gthreads = (long long)N * 64;
    int gblocks = (int)((gthreads + 255) / 256);
    if (hx_ok) {
      k_gatherbx<<<gblocks, 256, 0, stream>>>(Hb, offs, pack, Hx, N);
      k_vmean4x<<<NGRAPH * 4, 256, 0, stream>>>(Hx, batch, vmean, N);
      k_wprep<<<8, 256, 0, stream>>>(W, wt);
      k_mfmax<<<(N + 127) / 128, 256, 0, stream>>>((const uint4*)Hx, out, batch, vmean, wt, N);
      return;
    }
    if (bf_ok) {
      k_gatherb<<<gblocks, 256, 0, stream>>>(H, Hb, offs, pack, out, N);
    } else {
      k_gather<<<gblocks, 256, 0, stream>>>(H, offs, pack, out, N);
    }
  } else {
    vmean = (float*)d_ws;
    int n4 = N * DIM / 4;
    k_init<<<(n4 + 255) / 256, 256, 0, stream>>>((const float4*)H, (float4*)out, n4);
    long long sthreads = (long long)E * 32;
    k_scatter<<<(int)((sthreads + 255) / 256), 256, 0, stream>>>(H, src, dst, out, E);
  }

  k_vmean4<<<NGRAPH * 4, 256, 0, stream>>>(out, batch, vmean, N);

  if (wt_ok) {
    k_wprep<<<8, 256, 0, stream>>>(W, wt);
    k_mfma<<<(N + 127) / 128, 256, 0, stream>>>(out, batch, vmean, wt, N);
  } else {
    k_gemm<<<(N + TRR - 1) / TRR, 256, 0, stream>>>(out, batch, vmean, W, N);
  }
}